// Round 10
// baseline (254.043 us; speedup 1.0000x reference)
//
#include <hip/hip_runtime.h>
#include <hip/hip_bf16.h>

// BinaryLinear: out[131072,256] = x[131072,256] @ (sign(W)*scale)[256,256]^T + bias
// R6 post-mortem: LDS-read-bound (1:1 ds_read:MFMA, 1 block/CU from 128KiB LDS).
// R7 structure: B persistent in REGISTERS (128 VGPR/wave), no LDS, no barriers.
// Persistent grid (256 blocks, 1/CU), grid-stride over 16-row tiles, 1-tile-deep
// x prefetch. Per iter/CU: 16KB x read + 16KB out write vs ~300cy MFMA -> HBM-bound.

typedef __bf16 bf16_t;
typedef __attribute__((ext_vector_type(8))) __bf16 bf16x8;  // MFMA A/B fragment (4 VGPR)
typedef __attribute__((ext_vector_type(4))) float f32x4;    // MFMA C/D fragment

#define MROWS 131072
#define NDIM 256
#define KDIM 256
#define TROWS 16
#define NT (MROWS / TROWS)   // 8192 row-tiles
#define GRID 256             // persistent: 1 block/CU

// ---- Kernel 1: wb[o][i] = bf16(sign(W[o][i]))  (+1/-1/0, exact in bf16) ----
__global__ __launch_bounds__(256) void prep_w_kernel(const float* __restrict__ W,
                                                     bf16_t* __restrict__ wb) {
    int idx = blockIdx.x * 256 + threadIdx.x;   // 0 .. 65535
    float w = W[idx];
    wb[idx] = (bf16_t)((w > 0.0f) ? 1.0f : ((w < 0.0f) ? -1.0f : 0.0f));
}

__device__ inline bf16x8 cvt8(f32x4 lo, f32x4 hi) {
    bf16x8 r;
    r[0] = (bf16_t)lo.x; r[1] = (bf16_t)lo.y; r[2] = (bf16_t)lo.z; r[3] = (bf16_t)lo.w;
    r[4] = (bf16_t)hi.x; r[5] = (bf16_t)hi.y; r[6] = (bf16_t)hi.z; r[7] = (bf16_t)hi.w;
    return r;
}

// ---- Kernel 2: GEMM, B-in-registers, persistent blocks ----
// Block: 256 thr (4 waves). Wave w owns cols [w*64, w*64+64) for ALL rows.
// breg[ni][ks]: B-frag for col-tile ni, k-step ks — loaded once (static indexing
// only, so it stays in VGPRs). Each tile-iter: cvt prefetched x, issue next
// tile's 16 loads, 32 MFMA, 16 stores. Zero LDS, zero __syncthreads.
__global__ __launch_bounds__(256, 1) void bin_gemm_kernel(
        const float* __restrict__ x,
        const bf16_t* __restrict__ wb,
        const float* __restrict__ scale,
        const float* __restrict__ bias,
        float* __restrict__ out) {
    const int tid  = threadIdx.x;
    const int lane = tid & 63;
    const int wave = tid >> 6;
    const int lrow = lane & 15;      // frag row (A) / col (B,C)
    const int lk   = lane >> 4;      // k-group
    const int cb   = wave * 64;      // this wave's output-column base

    // ---- persistent B: 4 col-frags x 8 k-steps = 128 VGPR ----
    bf16x8 breg[4][8];
    #pragma unroll
    for (int ni = 0; ni < 4; ++ni) {
        const bf16_t* pb = wb + (size_t)(cb + ni * 16 + lrow) * KDIM + lk * 8;
        #pragma unroll
        for (int ks = 0; ks < 8; ++ks)
            breg[ni][ks] = *reinterpret_cast<const bf16x8*>(pb + ks * 32);
    }
    float sc[4], bi[4];
    #pragma unroll
    for (int ni = 0; ni < 4; ++ni) {
        sc[ni] = scale[cb + ni * 16 + lrow];
        bi[ni] = bias[cb + ni * 16 + lrow];
    }

    // ---- prologue: load first tile's x ----
    f32x4 xlo[8], xhi[8];
    {
        const float* p0 = x + ((size_t)blockIdx.x * TROWS + lrow) * KDIM + lk * 8;
        #pragma unroll
        for (int ks = 0; ks < 8; ++ks) {
            xlo[ks] = *reinterpret_cast<const f32x4*>(p0 + ks * 32);
            xhi[ks] = *reinterpret_cast<const f32x4*>(p0 + ks * 32 + 4);
        }
    }

    for (int t = blockIdx.x; t < NT; t += GRID) {
        // convert prefetched x -> bf16 A-frags (waits on loads issued last iter)
        bf16x8 a[8];
        #pragma unroll
        for (int ks = 0; ks < 8; ++ks) a[ks] = cvt8(xlo[ks], xhi[ks]);

        // issue next tile's loads (one full iteration of latency hiding)
        int tn = t + GRID;
        if (tn < NT) {
            const float* pn = x + ((size_t)tn * TROWS + lrow) * KDIM + lk * 8;
            #pragma unroll
            for (int ks = 0; ks < 8; ++ks) {
                xlo[ks] = *reinterpret_cast<const f32x4*>(pn + ks * 32);
                xhi[ks] = *reinterpret_cast<const f32x4*>(pn + ks * 32 + 4);
            }
        }

        // 32 MFMA: 4 independent acc chains (ni), ks-major for ILP
        f32x4 acc[4] = {};
        #pragma unroll
        for (int ks = 0; ks < 8; ++ks)
            #pragma unroll
            for (int ni = 0; ni < 4; ++ni)
                acc[ni] = __builtin_amdgcn_mfma_f32_16x16x32_bf16(
                              a[ks], breg[ni][ks], acc[ni], 0, 0, 0);

        // epilogue: out = acc * scale + bias (f32, regular stores)
        float* po = out + ((size_t)t * TROWS + lk * 4) * NDIM;
        #pragma unroll
        for (int ni = 0; ni < 4; ++ni) {
            int col = cb + ni * 16 + lrow;
            #pragma unroll
            for (int r = 0; r < 4; ++r)   // C/D: row=(lane>>4)*4+r, col=lane&15
                po[(size_t)r * NDIM + col] = acc[ni][r] * sc[ni] + bi[ni];
        }
    }
}

extern "C" void kernel_launch(void* const* d_in, const int* in_sizes, int n_in,
                              void* d_out, int out_size, void* d_ws, size_t ws_size,
                              hipStream_t stream) {
    const float* x     = (const float*)d_in[0];
    const float* W     = (const float*)d_in[1];
    const float* scale = (const float*)d_in[2];
    const float* bias  = (const float*)d_in[3];
    float*       out   = (float*)d_out;
    bf16_t*      wb    = (bf16_t*)d_ws;        // 256*256*2 = 128 KiB scratch

    prep_w_kernel<<<NDIM * KDIM / 256, 256, 0, stream>>>(W, wb);
    bin_gemm_kernel<<<GRID, 256, 0, stream>>>(x, wb, scale, bias, out);
}